// Round 4
// baseline (1107.609 us; speedup 1.0000x reference)
//
#include <hip/hip_runtime.h>
#include <hip/hip_bf16.h>

// Problem constants
#define Bb 256
#define Nn_ 17
#define CIN 3
#define HID 64
#define CCH 128        // HEADS*HID
#define Gg 16384       // B*S
#define Ee 81          // 64 edges + 17 self loops
#define LSTM_IN 2176   // 17*128
#define OUT_ 128
#define G4 512         // 4*OUT
#define NCLS 10
#define Tt 64
#define Mg (Gg * Nn_)  // 278528
#define GPB 8          // graphs per mega-block
#define ROWS 144       // GPB*18 (17 + 1 zero pad row per graph)

typedef unsigned short u16;
typedef unsigned int u32;
typedef __attribute__((ext_vector_type(8))) short bf16x8;
typedef __attribute__((ext_vector_type(4))) float f32x4;

__device__ __forceinline__ u16 f2bf(float f) {   // RNE fp32->bf16
    u32 u = __float_as_uint(f);
    u += 0x7fffu + ((u >> 16) & 1u);
    return (u16)(u >> 16);
}
__device__ __forceinline__ float bflo(u32 v) { return __uint_as_float(v << 16); }
__device__ __forceinline__ float bfhi(u32 v) { return __uint_as_float(v & 0xffff0000u); }

__device__ __forceinline__ void async16(const void* g, void* l) {
    __builtin_amdgcn_global_load_lds((__attribute__((address_space(1))) u32*)g,
                                     (__attribute__((address_space(3))) u32*)l, 16, 0, 0);
}

// ---------------- setup: build src/dst + dst-CSR
__global__ void k_setup(const int* __restrict__ edge_index, int* __restrict__ csr) {
    if (threadIdx.x == 0 && blockIdx.x == 0) {
        int* src = csr;
        int* dst = csr + Ee;
        int* off = csr + 2 * Ee;          // 162
        int* eid = csr + 2 * Ee + Nn_ + 1; // 180
        for (int e = 0; e < 64; e++) { src[e] = edge_index[e]; dst[e] = edge_index[64 + e]; }
        for (int n = 0; n < Nn_; n++) { src[64 + n] = n; dst[64 + n] = n; }
        int cnt[Nn_];
        for (int n = 0; n < Nn_; n++) cnt[n] = 0;
        for (int e = 0; e < Ee; e++) cnt[dst[e]]++;
        off[0] = 0;
        for (int n = 0; n < Nn_; n++) off[n + 1] = off[n] + cnt[n];
        int pos[Nn_];
        for (int n = 0; n < Nn_; n++) pos[n] = off[n];
        for (int e = 0; e < Ee; e++) eid[pos[dst[e]]++] = e;
    }
}

__global__ void k_convert(const float* __restrict__ in, u16* __restrict__ out, long n) {
    long i = (long)blockIdx.x * 256 + threadIdx.x;
    if (i < n) out[i] = f2bf(in[i]);
}
__global__ void k_convert_t128(const float* __restrict__ in, u16* __restrict__ out) {
    int i = blockIdx.x * 256 + threadIdx.x;
    int n = i >> 7, k = i & 127;
    out[i] = f2bf(in[k * 128 + n]);
}

// ================ GAT megakernel: 8 graphs per block, all 4 layers in LDS ================
__global__ __launch_bounds__(256, 2) void k_gat_mega(
    const float* __restrict__ x, const float* __restrict__ W0,
    const u16* __restrict__ wt1, const u16* __restrict__ wt2, const u16* __restrict__ wt3,
    const float* __restrict__ gas0, const float* __restrict__ gad0, const float* __restrict__ gb0,
    const float* __restrict__ gas1, const float* __restrict__ gad1, const float* __restrict__ gb1,
    const float* __restrict__ gas2, const float* __restrict__ gad2, const float* __restrict__ gb2,
    const float* __restrict__ gas3, const float* __restrict__ gad3, const float* __restrict__ gb3,
    const int* __restrict__ csr, u16* __restrict__ hout) {
    __shared__ __align__(16) u16 hB[ROWS * 128];       // 36.9 KB, XOR-chunk swizzled
    __shared__ float aS[GPB][34], aD[GPB][34];          // per (g, n*2+hh) dots
    __shared__ float ev[GPB][162];                      // edge scores / alpha
    __shared__ float mS[GPB][34], dS[GPB][34];          // softmax max/den
    __shared__ float avec[128], dvec[128], bvec[128];   // a_src, a_dst, bias (layer)
    __shared__ float w0s[384];
    __shared__ int srcS[Ee], dstS[Ee], offS[Nn_ + 1], eidS[Ee];

    const int t = threadIdx.x;
    const long g0 = (long)blockIdx.x * GPB;

    if (t < Ee) { srcS[t] = csr[t]; dstS[t] = csr[Ee + t]; eidS[t] = csr[180 + t]; }
    if (t < Nn_ + 1) offS[t] = csr[162 + t];
    for (int i = t; i < 384; i += 256) w0s[i] = W0[i];
    __syncthreads();

    // ---- layer 0 projection: h = x @ W0 (K=3), write bf16 swizzled; pad rows = 0
    for (int i = t; i < ROWS * 16; i += 256) {
        int row = i >> 4, cs = i & 15;
        int n = row % 18, gs = row / 18;
        union { uint4 qv; u16 s[8]; } pk;
        if (n == 17) {
            pk.qv = make_uint4(0, 0, 0, 0);
        } else {
            long xr = ((g0 + gs) * 17 + n) * 3;
            float x0 = x[xr], x1 = x[xr + 1], x2 = x[xr + 2];
#pragma unroll
            for (int j = 0; j < 8; j++) {
                int c = cs * 8 + j;
                pk.s[j] = f2bf(x0 * w0s[c] + x1 * w0s[128 + c] + x2 * w0s[256 + c]);
            }
        }
        *(uint4*)&hB[row * 128 + ((cs ^ (row & 7)) << 3)] = pk.qv;
    }

    const int w = t >> 6, lane = t & 63, q = lane >> 4, col = lane & 15;

#pragma unroll 1
    for (int L = 0; L < 4; L++) {
        if (L > 0) {
            // ---- in-place MFMA GEMM: hB = hB @ W_L  (per-wave row-tiles, in-place safe)
            const u16* wt = (L == 1) ? wt1 : (L == 2) ? wt2 : wt3;
            for (int mt = w; mt < 9; mt += 4) {
                f32x4 acc[8] = {};
                const int rowA = mt * 16 + col;
#pragma unroll
                for (int ks = 0; ks < 4; ks++) {
                    const int chA = (ks * 4 + q) ^ (rowA & 7);
                    bf16x8 af = *(const bf16x8*)&hB[rowA * 128 + chA * 8];
#pragma unroll
                    for (int nt = 0; nt < 8; nt++) {
                        bf16x8 bf = *(const bf16x8*)&wt[(nt * 16 + col) * 128 + ks * 32 + q * 8];
                        acc[nt] = __builtin_amdgcn_mfma_f32_16x16x32_bf16(af, bf, acc[nt], 0, 0, 0);
                    }
                }
#pragma unroll
                for (int nt = 0; nt < 8; nt++)
#pragma unroll
                    for (int r = 0; r < 4; r++) {
                        const int rw = mt * 16 + q * 4 + r;
                        const int c = nt * 16 + col;
                        hB[rw * 128 + (((c >> 3) ^ (rw & 7)) << 3) + (c & 7)] = f2bf(acc[nt][r]);
                    }
            }
        }
        // ---- stage layer attention vectors
        const float* ga = (L == 0) ? gas0 : (L == 1) ? gas1 : (L == 2) ? gas2 : gas3;
        const float* gd = (L == 0) ? gad0 : (L == 1) ? gad1 : (L == 2) ? gad2 : gad3;
        const float* gbv = (L == 0) ? gb0 : (L == 1) ? gb1 : (L == 2) ? gb2 : gb3;
        const int relu = (L == 0) || (L == 2);
        if (t < 128) { avec[t] = ga[t]; dvec[t] = gd[t]; }
        else bvec[t - 128] = gbv[t - 128];
        __syncthreads();   // also covers layer-0 write / GEMM write -> phase A reads

        // ---- phase A: per-(g,n,hh) dots  (272 items)
        for (int i = t; i < GPB * 34; i += 256) {
            const int gs = i / 34, rem = i % 34;
            const int n = rem >> 1, hh = rem & 1;
            const int row = gs * 18 + n;
            float s1 = 0.f, s2 = 0.f;
#pragma unroll
            for (int ch = 0; ch < 8; ch++) {
                const int chunk = hh * 8 + ch;
                uint4 v = *(const uint4*)&hB[row * 128 + ((chunk ^ (row & 7)) << 3)];
                const float* av = &avec[hh * 64 + ch * 8];
                const float* dv = &dvec[hh * 64 + ch * 8];
                float f0 = bflo(v.x), f1 = bfhi(v.x), f2 = bflo(v.y), f3 = bfhi(v.y);
                float f4 = bflo(v.z), f5 = bfhi(v.z), f6 = bflo(v.w), f7 = bfhi(v.w);
                s1 += f0 * av[0] + f1 * av[1] + f2 * av[2] + f3 * av[3]
                    + f4 * av[4] + f5 * av[5] + f6 * av[6] + f7 * av[7];
                s2 += f0 * dv[0] + f1 * dv[1] + f2 * dv[2] + f3 * dv[3]
                    + f4 * dv[4] + f5 * dv[5] + f6 * dv[6] + f7 * dv[7];
            }
            aS[gs][rem] = s1;
            aD[gs][rem] = s2;
        }
        __syncthreads();
        // ---- phase B: edge scores + leaky relu (1296 items)
        for (int i = t; i < GPB * 162; i += 256) {
            const int g = i / 162, rem = i % 162;
            const int e = rem >> 1, hh = rem & 1;
            float vv = aS[g][srcS[e] * 2 + hh] + aD[g][dstS[e] * 2 + hh];
            ev[g][rem] = (vv > 0.f) ? vv : 0.2f * vv;
        }
        __syncthreads();
        // ---- phase C: per-node max / denom (272 items)
        for (int i = t; i < GPB * 34; i += 256) {
            const int gs = i / 34, rem = i % 34;
            const int n = rem >> 1, hh = rem & 1;
            const int p0 = offS[n], p1 = offS[n + 1];
            float m = -1e30f;
            for (int p = p0; p < p1; p++) m = fmaxf(m, ev[gs][eidS[p] * 2 + hh]);
            float den = 0.f;
            for (int p = p0; p < p1; p++) den += expf(ev[gs][eidS[p] * 2 + hh] - m);
            mS[gs][rem] = m;
            dS[gs][rem] = den;
        }
        __syncthreads();
        // ---- phase D: alpha (1296 items)
        for (int i = t; i < GPB * 162; i += 256) {
            const int g = i / 162, rem = i % 162;
            const int e = rem >> 1, hh = rem & 1;
            const int n = dstS[e];
            ev[g][rem] = expf(ev[g][rem] - mS[g][n * 2 + hh]) / (dS[g][n * 2 + hh] + 1e-16f);
        }
        __syncthreads();
        // ---- phase E: aggregation, per column-half (reads done before writes via barrier)
#pragma unroll 1
        for (int hh = 0; hh < 2; hh++) {
            float ac0[17], ac1[17];
#pragma unroll
            for (int it = 0; it < 17; it++) {
                const int i = t + it * 256;          // < 4352
                const int cp = i & 31, nrem = i >> 5;
                const int n = nrem % 17, g = nrem / 17;
                const int c = hh * 64 + cp * 2;
                const int p0 = offS[n], p1 = offS[n + 1];
                float a0 = 0.f, a1 = 0.f;
                for (int p = p0; p < p1; p++) {
                    const int e = eidS[p];
                    const int sr = g * 18 + srcS[e];
                    u32 hv = *(const u32*)&hB[sr * 128 + (((c >> 3) ^ (sr & 7)) << 3) + (c & 7)];
                    float al = ev[g][e * 2 + hh];
                    a0 += al * bflo(hv);
                    a1 += al * bfhi(hv);
                }
                a0 += bvec[c];
                a1 += bvec[c + 1];
                if (relu) { a0 = fmaxf(a0, 0.f); a1 = fmaxf(a1, 0.f); }
                ac0[it] = a0;
                ac1[it] = a1;
            }
            __syncthreads();
#pragma unroll
            for (int it = 0; it < 17; it++) {
                const int i = t + it * 256;
                const int cp = i & 31, nrem = i >> 5;
                const int n = nrem % 17, g = nrem / 17;
                const int c = hh * 64 + cp * 2;
                const int rw = g * 18 + n;
                u32 pk = (u32)f2bf(ac0[it]) | ((u32)f2bf(ac1[it]) << 16);
                *(u32*)&hB[rw * 128 + (((c >> 3) ^ (rw & 7)) << 3) + (c & 7)] = pk;
            }
            __syncthreads();
        }
    }
    // ---- write out: [g][17][128] bf16 (coalesced u32)
    u32* og = (u32*)hout + g0 * 1088;
    for (int i = t; i < GPB * 1088; i += 256) {
        const int cp = i & 63, n = (i >> 6) % 17, gs = i / 1088;
        const int c = cp * 2, row = gs * 18 + n;
        og[gs * 1088 + n * 64 + cp] =
            *(const u32*)&hB[row * 128 + (((c >> 3) ^ (row & 7)) << 3) + (c & 7)];
    }
}

// ---------------- bf16 MFMA GEMM: C[M,ldc] = A[M,K]bf16 @ Bt[N,K]bf16^T + b1[n]+b2[n] (fp32 out)
__global__ __launch_bounds__(256) void k_gemm_mfma(const u16* __restrict__ A,
                                                   const u16* __restrict__ Bt,
                                                   float* __restrict__ Cm,
                                                   const float* __restrict__ b1,
                                                   const float* __restrict__ b2,
                                                   int K, int ldc) {
    __shared__ u16 ldsA[128 * 64];
    __shared__ u16 ldsB[128 * 64];
    const int w = threadIdx.x >> 6;
    const int lane = threadIdx.x & 63;
    const long bm = (long)blockIdx.x * 128;
    const int bn = blockIdx.y * 128;
    const int wm = (w & 1) * 64, wn = (w >> 1) * 64;
    const int q = lane >> 4, col = lane & 15;
    f32x4 acc[4][4] = {};
    for (int k0 = 0; k0 < K; k0 += 64) {
#pragma unroll
        for (int i = 0; i < 4; i++) {
            const int slot = (w * 4 + i) * 64 + lane;
            const int r = slot >> 3, cs = slot & 7;
            const int cg = cs ^ (r & 7);
            async16(A + (bm + r) * (long)K + k0 + cg * 8, ldsA + (w * 4 + i) * 512);
            async16(Bt + (long)(bn + r) * K + k0 + cg * 8, ldsB + (w * 4 + i) * 512);
        }
        __syncthreads();
#pragma unroll
        for (int kk = 0; kk < 2; kk++) {
            bf16x8 af[4], bfr[4];
#pragma unroll
            for (int mt = 0; mt < 4; mt++) {
                const int m = wm + mt * 16 + col;
                const int cs = (kk * 4 + q) ^ (m & 7);
                af[mt] = *(const bf16x8*)&ldsA[m * 64 + cs * 8];
            }
#pragma unroll
            for (int nt = 0; nt < 4; nt++) {
                const int n = wn + nt * 16 + col;
                const int cs = (kk * 4 + q) ^ (n & 7);
                bfr[nt] = *(const bf16x8*)&ldsB[n * 64 + cs * 8];
            }
#pragma unroll
            for (int mt = 0; mt < 4; mt++)
#pragma unroll
                for (int nt = 0; nt < 4; nt++)
                    acc[mt][nt] = __builtin_amdgcn_mfma_f32_16x16x32_bf16(af[mt], bfr[nt], acc[mt][nt], 0, 0, 0);
        }
        __syncthreads();
    }
#pragma unroll
    for (int mt = 0; mt < 4; mt++)
#pragma unroll
        for (int nt = 0; nt < 4; nt++) {
            const int cg = bn + wn + nt * 16 + col;
            const float bb = b1[cg] + b2[cg];
#pragma unroll
            for (int r = 0; r < 4; r++) {
                const long rg = bm + wm + mt * 16 + q * 4 + r;
                Cm[rg * ldc + cg] = acc[mt][nt][r] + bb;
            }
        }
}

// ---------------- LSTM recurrence
template <int OBF16>
__global__ __launch_bounds__(512, 1) void k_lstm(const float* __restrict__ XW,
                                                 const float* __restrict__ whh,
                                                 void* __restrict__ hseq) {
    const int b = blockIdx.x, j = threadIdx.x;
    float4 w[32];
#pragma unroll
    for (int k = 0; k < 32; k++) w[k] = ((const float4*)(whh + (long)j * OUT_))[k];
    __shared__ __align__(16) float h_s[OUT_];
    __shared__ float c_s[OUT_];
    __shared__ float gate_s[G4];
    if (j < OUT_) { h_s[j] = 0.f; c_s[j] = 0.f; }
    __syncthreads();
    for (int t = 0; t < Tt; t++) {
        float acc = XW[((long)b * Tt + t) * G4 + j];
#pragma unroll
        for (int k = 0; k < 32; k++) {
            float4 hv = ((const float4*)h_s)[k];
            acc += w[k].x * hv.x + w[k].y * hv.y + w[k].z * hv.z + w[k].w * hv.w;
        }
        gate_s[j] = acc;
        __syncthreads();
        if (j < OUT_) {
            float gi = gate_s[j], gf = gate_s[OUT_ + j], gg = gate_s[2 * OUT_ + j], go = gate_s[3 * OUT_ + j];
            float si = 1.f / (1.f + expf(-gi));
            float sf = 1.f / (1.f + expf(-gf));
            float so = 1.f / (1.f + expf(-go));
            float c = sf * c_s[j] + si * tanhf(gg);
            float hh = so * tanhf(c);
            c_s[j] = c;
            h_s[j] = hh;
            long idx = ((long)b * Tt + t) * OUT_ + j;
            if (OBF16) ((u16*)hseq)[idx] = f2bf(hh);
            else       ((float*)hseq)[idx] = hh;
        }
        __syncthreads();
    }
}

// ---------------- attention pooling + FC
__global__ __launch_bounds__(64) void k_attn_fc(const float* __restrict__ h2,
                                                const float* __restrict__ attn_w,
                                                const float* __restrict__ attn_b,
                                                const float* __restrict__ fc_w,
                                                const float* __restrict__ fc_b,
                                                float* __restrict__ out) {
    const int b = blockIdx.x, t = threadIdx.x;
    __shared__ float aw[Tt];
    __shared__ float ctx[OUT_];
    const float* hb = h2 + (long)b * Tt * OUT_;
    float acc = 0.f;
    for (int d = 0; d < OUT_; d++) acc += hb[t * OUT_ + d] * attn_w[d];
    float sc = tanhf(acc + attn_b[0]);
    float m = sc;
#pragma unroll
    for (int o = 32; o > 0; o >>= 1) m = fmaxf(m, __shfl_xor(m, o));
    float ex = expf(sc - m);
    float sum = ex;
#pragma unroll
    for (int o = 32; o > 0; o >>= 1) sum += __shfl_xor(sum, o);
    aw[t] = ex / sum;
    __syncthreads();
    for (int d = t; d < OUT_; d += 64) {
        float c = 0.f;
        for (int tt = 0; tt < Tt; tt++) c += aw[tt] * hb[tt * OUT_ + d];
        ctx[d] = c;
    }
    __syncthreads();
    if (t < NCLS) {
        float o = fc_b[t];
        for (int d = 0; d < OUT_; d++) o += ctx[d] * fc_w[t * OUT_ + d];
        out[b * NCLS + t] = o;
    }
}

extern "C" void kernel_launch(void* const* d_in, const int* in_sizes, int n_in,
                              void* d_out, int out_size, void* d_ws, size_t ws_size,
                              hipStream_t stream) {
    const float* x          = (const float*)d_in[0];
    const int*   edge_index = (const int*)d_in[1];
    const float* gw[4]  = {(const float*)d_in[2], (const float*)d_in[6], (const float*)d_in[10], (const float*)d_in[14]};
    const float* gas[4] = {(const float*)d_in[3], (const float*)d_in[7], (const float*)d_in[11], (const float*)d_in[15]};
    const float* gad[4] = {(const float*)d_in[4], (const float*)d_in[8], (const float*)d_in[12], (const float*)d_in[16]};
    const float* gb[4]  = {(const float*)d_in[5], (const float*)d_in[9], (const float*)d_in[13], (const float*)d_in[17]};
    const float* wih0 = (const float*)d_in[18];
    const float* whh0 = (const float*)d_in[19];
    const float* bih0 = (const float*)d_in[20];
    const float* bhh0 = (const float*)d_in[21];
    const float* wih1 = (const float*)d_in[22];
    const float* whh1 = (const float*)d_in[23];
    const float* bih1 = (const float*)d_in[24];
    const float* bhh1 = (const float*)d_in[25];
    const float* attn_w = (const float*)d_in[26];
    const float* attn_b = (const float*)d_in[27];
    const float* fc_w   = (const float*)d_in[28];
    const float* fc_b   = (const float*)d_in[29];
    float* out = (float*)d_out;
    char* p = (char*)d_ws;

    u16*   hbuf  = (u16*)(p + 0L);             // Mg*128 bf16 = 71,303,168 B
    float* XW0   = (float*)(p + 71303168L);
    float* XW1   = (float*)(p + 104857600L);
    float* h2s   = (float*)(p + 138412032L);
    u16*   h1s   = (u16*)(p + 146800640L);
    u16*   wih0b = (u16*)(p + 150994944L);
    u16*   wih1b = (u16*)(p + 153223168L);
    u16*   wt1   = (u16*)(p + 153354240L);
    u16*   wt2   = (u16*)(p + 153387008L);
    u16*   wt3   = (u16*)(p + 153419776L);
    int*   csr   = (int*)(p + 153452544L);

    k_setup<<<1, 1, 0, stream>>>(edge_index, csr);
    k_convert_t128<<<64, 256, 0, stream>>>(gw[1], wt1);
    k_convert_t128<<<64, 256, 0, stream>>>(gw[2], wt2);
    k_convert_t128<<<64, 256, 0, stream>>>(gw[3], wt3);
    k_convert<<<(512 * 2176 + 255) / 256, 256, 0, stream>>>(wih0, wih0b, 512L * 2176);
    k_convert<<<(512 * 128 + 255) / 256, 256, 0, stream>>>(wih1, wih1b, 512L * 128);

    // fused GAT stack (all 4 layers) -> hbuf [16384, 2176] bf16
    k_gat_mega<<<Gg / GPB, 256, 0, stream>>>(x, gw[0], wt1, wt2, wt3,
                                             gas[0], gad[0], gb[0], gas[1], gad[1], gb[1],
                                             gas[2], gad[2], gb[2], gas[3], gad[3], gb[3],
                                             csr, hbuf);

    // LSTM layer 0
    k_gemm_mfma<<<dim3(Gg / 128, 4), 256, 0, stream>>>(hbuf, wih0b, XW0, bih0, bhh0, LSTM_IN, G4);
    k_lstm<1><<<Bb, 512, 0, stream>>>(XW0, whh0, h1s);
    // LSTM layer 1
    k_gemm_mfma<<<dim3(Gg / 128, 4), 256, 0, stream>>>(h1s, wih1b, XW1, bih1, bhh1, OUT_, G4);
    k_lstm<0><<<Bb, 512, 0, stream>>>(XW1, whh1, h2s);

    k_attn_fc<<<Bb, 64, 0, stream>>>(h2s, attn_w, attn_b, fc_w, fc_b, out);
}

// Round 7
// 882.024 us; speedup vs baseline: 1.2558x; 1.2558x over previous
//
#include <hip/hip_runtime.h>
#include <hip/hip_bf16.h>

// Problem constants
#define Bb 256
#define Nn_ 17
#define CIN 3
#define HID 64
#define CCH 128        // HEADS*HID
#define Gg 16384       // B*S
#define Ee 81          // 64 edges + 17 self loops
#define LSTM_IN 2176   // 17*128
#define OUT_ 128
#define G4 512         // 4*OUT
#define NCLS 10
#define Tt 64
#define Mg (Gg * Nn_)  // 278528

typedef unsigned short u16;
typedef unsigned int u32;
typedef __attribute__((ext_vector_type(8))) short bf16x8;
typedef __attribute__((ext_vector_type(4))) float f32x4;

__device__ __forceinline__ u16 f2bf(float f) {   // RNE fp32->bf16
    u32 u = __float_as_uint(f);
    u += 0x7fffu + ((u >> 16) & 1u);
    return (u16)(u >> 16);
}
__device__ __forceinline__ float bflo(u32 v) { return __uint_as_float(v << 16); }
__device__ __forceinline__ float bfhi(u32 v) { return __uint_as_float(v & 0xffff0000u); }

__device__ __forceinline__ void async16(const void* g, void* l) {
    __builtin_amdgcn_global_load_lds((__attribute__((address_space(1))) u32*)g,
                                     (__attribute__((address_space(3))) u32*)l, 16, 0, 0);
}

// ---------------- setup: build src/dst + dst-CSR
__global__ void k_setup(const int* __restrict__ edge_index, int* __restrict__ csr) {
    if (threadIdx.x == 0 && blockIdx.x == 0) {
        int* src = csr;                    // [81]
        int* dst = csr + Ee;               // [81]
        int* off = csr + 2 * Ee;           // [18]
        int* eid = csr + 2 * Ee + Nn_ + 1; // [81]
        for (int e = 0; e < 64; e++) { src[e] = edge_index[e]; dst[e] = edge_index[64 + e]; }
        for (int n = 0; n < Nn_; n++) { src[64 + n] = n; dst[64 + n] = n; }
        int cnt[Nn_];
        for (int n = 0; n < Nn_; n++) cnt[n] = 0;
        for (int e = 0; e < Ee; e++) cnt[dst[e]]++;
        off[0] = 0;
        for (int n = 0; n < Nn_; n++) off[n + 1] = off[n] + cnt[n];
        int pos[Nn_];
        for (int n = 0; n < Nn_; n++) pos[n] = off[n];
        for (int e = 0; e < Ee; e++) eid[pos[dst[e]]++] = e;
    }
}

__global__ void k_convert(const float* __restrict__ in, u16* __restrict__ out, long n) {
    long i = (long)blockIdx.x * 256 + threadIdx.x;
    if (i < n) out[i] = f2bf(in[i]);
}
// 128x128 weight: [k][n] -> bf16 [n][k] (transpose for MFMA B-operand)
__global__ void k_convert_t128(const float* __restrict__ in, u16* __restrict__ out) {
    int i = blockIdx.x * 256 + threadIdx.x;  // over 16384
    int n = i >> 7, k = i & 127;
    out[i] = f2bf(in[k * 128 + n]);
}

// ---------------- GAT layer 0: h[Mg,128]=x@W0 (bf16) + aux[Mg,4]=x@(W0@a) (fp32)
__global__ __launch_bounds__(256) void k_l0(const float* __restrict__ x,
                                            const float* __restrict__ W0,
                                            const float* __restrict__ gas0,
                                            const float* __restrict__ gad0,
                                            u16* __restrict__ h, float* __restrict__ aux) {
    __shared__ float ws[3 * 128];
    __shared__ float w0a[12];   // [ci][j]  j: src_h0,src_h1,dst_h0,dst_h1
    const int t = threadIdx.x;
    for (int i = t; i < 384; i += 256) ws[i] = W0[i];
    __syncthreads();
    if (t < 12) {
        int ci = t >> 2, j = t & 3;
        const float* a = (j < 2) ? gas0 : gad0;
        int hh = j & 1;
        float s = 0.f;
        for (int d = 0; d < HID; d++) s += ws[ci * 128 + hh * 64 + d] * a[hh * 64 + d];
        w0a[t] = s;
    }
    __syncthreads();
    const long row = (long)blockIdx.x * 16 + (t >> 4);
    const int c0 = (t & 15) * 8;
    const float x0 = x[row * 3 + 0], x1 = x[row * 3 + 1], x2 = x[row * 3 + 2];
    union { uint4 u; u16 s[8]; } o;
#pragma unroll
    for (int j = 0; j < 8; j++)
        o.s[j] = f2bf(x0 * ws[c0 + j] + x1 * ws[128 + c0 + j] + x2 * ws[256 + c0 + j]);
    *(uint4*)(h + row * 128 + c0) = o.u;
    if ((t & 15) < 4) {
        int j = t & 3;
        aux[row * 4 + j] = x0 * w0a[j] + x1 * w0a[4 + j] + x2 * w0a[8 + j];
    }
}

// ---------------- GAT MFMA GEMM (in-place): hbuf = hbuf @ W ; aux = fp32 dots vs a_src/a_dst
// Block = 128 rows, K=128 single pass. A staged to LDS (XOR-swizzled) via global_load_lds;
// B-frags from global (L2-hot 32 KB weight). Attention dots computed in the epilogue in FP32
// from the pre-quantization accumulators (accuracy: round-5's bf16 fold was 1.4e-2, over thr).
// In-place safe: full output width per block, row-disjoint blocks, A reads staged before writes.
__global__ __launch_bounds__(256) void k_gemm_gat(u16* __restrict__ HB,
                                                  const u16* __restrict__ Wt,
                                                  const float* __restrict__ a_src,
                                                  const float* __restrict__ a_dst,
                                                  float* __restrict__ aux) {
    __shared__ u16 ldsA[128 * 128];  // 32 KB
    __shared__ float avec[128], dvec[128];
    const int t = threadIdx.x;
    const int w = t >> 6, lane = t & 63;
    const int q = lane >> 4, col = lane & 15;
    const long bm = (long)blockIdx.x * 128;
    const int wm = w * 32;

    if (t < 128) avec[t] = a_src[t];
    else dvec[t - 128] = a_dst[t - 128];

    // stage A: 2048 chunk-slots of 16B, 8 async16 per thread
#pragma unroll
    for (int i = 0; i < 8; i++) {
        const int slot = (w * 8 + i) * 64 + lane;
        const int r = slot >> 4, cs = slot & 15;
        const int cg = cs ^ (r & 15);
        async16(HB + (bm + r) * 128 + cg * 8, ldsA + (w * 8 + i) * 512);
    }
    __syncthreads();

    f32x4 acc[2][8] = {};
#pragma unroll
    for (int ks = 0; ks < 4; ks++) {
        const int ck = ks * 4 + q;
        bf16x8 af[2];
#pragma unroll
        for (int mt = 0; mt < 2; mt++) {
            const int m = wm + mt * 16 + col;
            af[mt] = *(const bf16x8*)&ldsA[m * 128 + ((ck ^ (m & 15)) << 3)];
        }
#pragma unroll
        for (int nt = 0; nt < 8; nt++) {
            bf16x8 bf = *(const bf16x8*)&Wt[(nt * 16 + col) * 128 + ck * 8];
            acc[0][nt] = __builtin_amdgcn_mfma_f32_16x16x32_bf16(af[0], bf, acc[0][nt], 0, 0, 0);
            acc[1][nt] = __builtin_amdgcn_mfma_f32_16x16x32_bf16(af[1], bf, acc[1][nt], 0, 0, 0);
        }
    }
    __syncthreads();
#pragma unroll
    for (int mt = 0; mt < 2; mt++) {
        // h output (bf16, in-place)
#pragma unroll
        for (int nt = 0; nt < 8; nt++) {
            const int cg = nt * 16 + col;
#pragma unroll
            for (int r = 0; r < 4; r++) {
                const long rg = bm + wm + mt * 16 + q * 4 + r;
                HB[rg * 128 + cg] = f2bf(acc[mt][nt][r]);
            }
        }
        // fp32 attention dots: row rg's 128 cols live in this wave's 16 col-lanes (same q)
#pragma unroll
        for (int r = 0; r < 4; r++) {
            float s0 = 0.f, s1 = 0.f, d0 = 0.f, d1 = 0.f;
#pragma unroll
            for (int nt = 0; nt < 4; nt++) {
                const float v = acc[mt][nt][r];
                s0 += v * avec[nt * 16 + col];
                d0 += v * dvec[nt * 16 + col];
            }
#pragma unroll
            for (int nt = 4; nt < 8; nt++) {
                const float v = acc[mt][nt][r];
                s1 += v * avec[nt * 16 + col];
                d1 += v * dvec[nt * 16 + col];
            }
#pragma unroll
            for (int o = 1; o < 16; o <<= 1) {  // butterfly across col lanes (same q)
                s0 += __shfl_xor(s0, o);
                s1 += __shfl_xor(s1, o);
                d0 += __shfl_xor(d0, o);
                d1 += __shfl_xor(d1, o);
            }
            if (col == 0) {
                const long rg = bm + wm + mt * 16 + q * 4 + r;
                aux[rg * 4 + 0] = s0;
                aux[rg * 4 + 1] = s1;
                aux[rg * 4 + 2] = d0;
                aux[rg * 4 + 3] = d1;
            }
        }
    }
}

// ---------------- GAT attention (4 graphs/block): softmax over precomputed dots + aggregation
#define GPB 4
__global__ __launch_bounds__(256) void k_gat_attn(u16* __restrict__ h,
                                                  const float* __restrict__ aux,
                                                  const float* __restrict__ bias,
                                                  const int* __restrict__ csr,
                                                  int relu_flag) {
    __shared__ u32 hs[GPB * Nn_ * 64];       // 17,408 B  [g][n][cp]
    __shared__ float asd[GPB * Nn_ * 4];     // [g][n][4]
    __shared__ float ev[GPB][162];
    __shared__ float mS[GPB][34], dS[GPB][34];
    __shared__ float bvec[128];
    __shared__ int srcS[Ee], dstS[Ee], offS[Nn_ + 1], eidS[Ee];
    const int t = threadIdx.x;
    const long g0 = (long)blockIdx.x * GPB;

    if (t < Ee) { srcS[t] = csr[t]; dstS[t] = csr[Ee + t]; eidS[t] = csr[180 + t]; }
    if (t >= 128 && t < 128 + Nn_ + 1) offS[t - 128] = csr[162 + t - 128];
    if (t < 128) bvec[t] = bias[t];
    {
        const u32* hg = (const u32*)h + g0 * 1088;
#pragma unroll
        for (int it = 0; it < 17; it++) hs[t + it * 256] = hg[t + it * 256];
        const float* ag = aux + g0 * 68;
        if (t < 272) asd[t] = ag[t];
    }
    __syncthreads();
    // edge scores + leaky relu: 648 items
    for (int i = t; i < GPB * 162; i += 256) {
        const int g = i / 162, rem = i % 162, e = rem >> 1, hh = rem & 1;
        float v = asd[(g * Nn_ + srcS[e]) * 4 + hh] + asd[(g * Nn_ + dstS[e]) * 4 + 2 + hh];
        ev[g][rem] = (v > 0.f) ? v : 0.2f * v;
    }
    __syncthreads();
    // per-node max/den: 136 items
    if (t < GPB * 34) {
        const int g = t / 34, rem = t % 34, n = rem >> 1, hh = rem & 1;
        const int p0 = offS[n], p1 = offS[n + 1];
        float m = -1e30f;
        for (int p = p0; p < p1; p++) m = fmaxf(m, ev[g][eidS[p] * 2 + hh]);
        float den = 0.f;
        for (int p = p0; p < p1; p++) den += expf(ev[g][eidS[p] * 2 + hh] - m);
        mS[g][rem] = m;
        dS[g][rem] = den;
    }
    __syncthreads();
    // alpha: 648 items
    for (int i = t; i < GPB * 162; i += 256) {
        const int g = i / 162, rem = i % 162, e = rem >> 1, hh = rem & 1;
        const int n = dstS[e];
        ev[g][rem] = expf(ev[g][rem] - mS[g][n * 2 + hh]) / (dS[g][n * 2 + hh] + 1e-16f);
    }
    __syncthreads();
    // aggregation: 4352 items; item = (graph, node, column-pair), stride-1 LDS reads
    u32* hg = (u32*)h + g0 * 1088;
#pragma unroll
    for (int it = 0; it < 17; it++) {
        const int i = t + it * 256;          // < 4352
        const int gg = i / 1088, rr = i % 1088;
        const int n = rr >> 6, cp = rr & 63, hh = cp >> 5;
        const int p0 = offS[n], p1 = offS[n + 1];
        float a0 = 0.f, a1 = 0.f;
        for (int p = p0; p < p1; p++) {
            const int e = eidS[p];
            const u32 hv = hs[(gg * Nn_ + srcS[e]) * 64 + cp];
            const float al = ev[gg][e * 2 + hh];
            a0 += al * bflo(hv);
            a1 += al * bfhi(hv);
        }
        a0 += bvec[cp * 2];
        a1 += bvec[cp * 2 + 1];
        if (relu_flag) { a0 = fmaxf(a0, 0.f); a1 = fmaxf(a1, 0.f); }
        hg[gg * 1088 + n * 64 + cp] = (u32)f2bf(a0) | ((u32)f2bf(a1) << 16);
    }
}

// ---------------- bf16 MFMA GEMM: C[M,ldc] = A[M,K]bf16 @ Bt[N,K]bf16^T + b1[n]+b2[n] (fp32)
__global__ __launch_bounds__(256) void k_gemm_mfma(const u16* __restrict__ A,
                                                   const u16* __restrict__ Bt,
                                                   float* __restrict__ Cm,
                                                   const float* __restrict__ b1,
                                                   const float* __restrict__ b2,
                                                   int K, int ldc) {
    __shared__ u16 ldsA[128 * 64];
    __shared__ u16 ldsB[128 * 64];
    const int w = threadIdx.x >> 6;
    const int lane = threadIdx.x & 63;
    const long bm = (long)blockIdx.x * 128;
    const int bn = blockIdx.y * 128;
    const int wm = (w & 1) * 64, wn = (w >> 1) * 64;
    const int q = lane >> 4, col = lane & 15;
    f32x4 acc[4][4] = {};
    for (int k0 = 0; k0 < K; k0 += 64) {
#pragma unroll
        for (int i = 0; i < 4; i++) {
            const int slot = (w * 4 + i) * 64 + lane;
            const int r = slot >> 3, cs = slot & 7;
            const int cg = cs ^ (r & 7);
            async16(A + (bm + r) * (long)K + k0 + cg * 8, ldsA + (w * 4 + i) * 512);
            async16(Bt + (long)(bn + r) * K + k0 + cg * 8, ldsB + (w * 4 + i) * 512);
        }
        __syncthreads();
#pragma unroll
        for (int kk = 0; kk < 2; kk++) {
            bf16x8 af[4], bfr[4];
#pragma unroll
            for (int mt = 0; mt < 4; mt++) {
                const int m = wm + mt * 16 + col;
                const int cs = (kk * 4 + q) ^ (m & 7);
                af[mt] = *(const bf16x8*)&ldsA[m * 64 + cs * 8];
            }
#pragma unroll
            for (int nt = 0; nt < 4; nt++) {
                const int n = wn + nt * 16 + col;
                const int cs = (kk * 4 + q) ^ (n & 7);
                bfr[nt] = *(const bf16x8*)&ldsB[n * 64 + cs * 8];
            }
#pragma unroll
            for (int mt = 0; mt < 4; mt++)
#pragma unroll
                for (int nt = 0; nt < 4; nt++)
                    acc[mt][nt] = __builtin_amdgcn_mfma_f32_16x16x32_bf16(af[mt], bfr[nt], acc[mt][nt], 0, 0, 0);
        }
        __syncthreads();
    }
#pragma unroll
    for (int mt = 0; mt < 4; mt++)
#pragma unroll
        for (int nt = 0; nt < 4; nt++) {
            const int cg = bn + wn + nt * 16 + col;
            const float bb = b1[cg] + b2[cg];
#pragma unroll
            for (int r = 0; r < 4; r++) {
                const long rg = bm + wm + mt * 16 + q * 4 + r;
                Cm[rg * ldc + cg] = acc[mt][nt][r] + bb;
            }
        }
}

// ---------------- LSTM recurrence
template <int OBF16>
__global__ __launch_bounds__(512, 1) void k_lstm(const float* __restrict__ XW,
                                                 const float* __restrict__ whh,
                                                 void* __restrict__ hseq) {
    const int b = blockIdx.x, j = threadIdx.x;
    float4 w[32];
#pragma unroll
    for (int k = 0; k < 32; k++) w[k] = ((const float4*)(whh + (long)j * OUT_))[k];
    __shared__ __align__(16) float h_s[OUT_];
    __shared__ float c_s[OUT_];
    __shared__ float gate_s[G4];
    if (j < OUT_) { h_s[j] = 0.f; c_s[j] = 0.f; }
    __syncthreads();
    for (int t = 0; t < Tt; t++) {
        float acc = XW[((long)b * Tt + t) * G4 + j];
#pragma unroll
        for (int k = 0; k < 32; k++) {
            float4 hv = ((const float4*)h_s)[k];
            acc += w[k].x * hv.x + w[k].y * hv.y + w[k].z * hv.z + w[k].w * hv.w;
        }
        gate_s[j] = acc;
        __syncthreads();
        if (j < OUT_) {
            float gi = gate_s[j], gf = gate_s[OUT_ + j], gg = gate_s[2 * OUT_ + j], go = gate_s[3 * OUT_ + j];
            float si = 1.f / (1.f + expf(-gi));
            float sf = 1.f / (1.f + expf(-gf));
            float so = 1.f / (1.f + expf(-go));
            float c = sf * c_s[j] + si * tanhf(gg);
            float hh = so * tanhf(c);
            c_s[j] = c;
            h_s[j] = hh;
            long idx = ((long)b * Tt + t) * OUT_ + j;
            if (OBF16) ((u16*)hseq)[idx] = f2bf(hh);
            else       ((float*)hseq)[idx] = hh;
        }
        __syncthreads();
    }
}

// ---------------- attention pooling + FC
__global__ __launch_bounds__(64) void k_attn_fc(const float* __restrict__ h2,
                                                const float* __restrict__ attn_w,
                                                const float* __restrict__ attn_b,
                                                const float* __restrict__ fc_w,
                                                const float* __restrict__ fc_b,
                                                float* __restrict__ out) {
    const int b = blockIdx.x, t = threadIdx.x;
    __shared__ float aw[Tt];
    __shared__ float ctx[OUT_];
    const float* hb = h2 + (long)b * Tt * OUT_;
    float acc = 0.f;
    for (int d = 0; d < OUT_; d++) acc += hb[t * OUT_ + d] * attn_w[d];
    float sc = tanhf(acc + attn_b[0]);
    float m = sc;
#pragma unroll
    for (int o = 32; o > 0; o >>= 1) m = fmaxf(m, __shfl_xor(m, o));
    float ex = expf(sc - m);
    float sum = ex;
#pragma unroll
    for (int o = 32; o > 0; o >>= 1) sum += __shfl_xor(sum, o);
    aw[t] = ex / sum;
    __syncthreads();
    for (int d = t; d < OUT_; d += 64) {
        float c = 0.f;
        for (int tt = 0; tt < Tt; tt++) c += aw[tt] * hb[tt * OUT_ + d];
        ctx[d] = c;
    }
    __syncthreads();
    if (t < NCLS) {
        float o = fc_b[t];
        for (int d = 0; d < OUT_; d++) o += ctx[d] * fc_w[t * OUT_ + d];
        out[b * NCLS + t] = o;
    }
}

extern "C" void kernel_launch(void* const* d_in, const int* in_sizes, int n_in,
                              void* d_out, int out_size, void* d_ws, size_t ws_size,
                              hipStream_t stream) {
    const float* x          = (const float*)d_in[0];
    const int*   edge_index = (const int*)d_in[1];
    const float* gw[4]  = {(const float*)d_in[2], (const float*)d_in[6], (const float*)d_in[10], (const float*)d_in[14]};
    const float* gas[4] = {(const float*)d_in[3], (const float*)d_in[7], (const float*)d_in[11], (const float*)d_in[15]};
    const float* gad[4] = {(const float*)d_in[4], (const float*)d_in[8], (const float*)d_in[12], (const float*)d_in[16]};
    const float* gb[4]  = {(const float*)d_in[5], (const float*)d_in[9], (const float*)d_in[13], (const float*)d_in[17]};
    const float* wih0 = (const float*)d_in[18];
    const float* whh0 = (const float*)d_in[19];
    const float* bih0 = (const float*)d_in[20];
    const float* bhh0 = (const float*)d_in[21];
    const float* wih1 = (const float*)d_in[22];
    const float* whh1 = (const float*)d_in[23];
    const float* bih1 = (const float*)d_in[24];
    const float* bhh1 = (const float*)d_in[25];
    const float* attn_w = (const float*)d_in[26];
    const float* attn_b = (const float*)d_in[27];
    const float* fc_w   = (const float*)d_in[28];
    const float* fc_b   = (const float*)d_in[29];
    float* out = (float*)d_out;
    char* p = (char*)d_ws;

    // Workspace (~158 MB; 176.2 MB proven OK in round 2)
    u16*   hbuf  = (u16*)(p + 0L);              // 71,303,168 B
    float* aux   = (float*)(p + 71303168L);     //  4,456,448 B  [Mg,4] fp32
    float* XW0   = (float*)(p + 75759616L);     // 33,554,432 B
    float* XW1   = (float*)(p + 109314048L);    // 33,554,432 B
    float* h2s   = (float*)(p + 142868480L);    //  8,388,608 B
    u16*   h1s   = (u16*)(p + 151257088L);      //  4,194,304 B
    u16*   wih0b = (u16*)(p + 155451392L);      //  2,228,224 B
    u16*   wih1b = (u16*)(p + 157679616L);      //    131,072 B
    u16*   wt1   = (u16*)(p + 157810688L);      //     32,768 B (x3)
    u16*   wt2   = (u16*)(p + 157843456L);
    u16*   wt3   = (u16*)(p + 157876224L);
    int*   csr   = (int*)(p + 157908992L);      //      1,044 B

    k_setup<<<1, 1, 0, stream>>>(edge_index, csr);
    k_convert_t128<<<64, 256, 0, stream>>>(gw[1], wt1);
    k_convert_t128<<<64, 256, 0, stream>>>(gw[2], wt2);
    k_convert_t128<<<64, 256, 0, stream>>>(gw[3], wt3);
    k_convert<<<(512 * 2176 + 255) / 256, 256, 0, stream>>>(wih0, wih0b, 512L * 2176);
    k_convert<<<(512 * 128 + 255) / 256, 256, 0, stream>>>(wih1, wih1b, 512L * 128);

    // GAT layer 0 projection (+fp32 attn dots) then attention
    k_l0<<<Mg / 16, 256, 0, stream>>>(x, gw[0], gas[0], gad[0], hbuf, aux);
    k_gat_attn<<<Gg / GPB, 256, 0, stream>>>(hbuf, aux, gb[0], csr, 1);
    // layers 1..3: in-place MFMA GEMM with fp32 dot epilogue, then attention
    k_gemm_gat<<<Mg / 128, 256, 0, stream>>>(hbuf, wt1, gas[1], gad[1], aux);
    k_gat_attn<<<Gg / GPB, 256, 0, stream>>>(hbuf, aux, gb[1], csr, 0);
    k_gemm_gat<<<Mg / 128, 256, 0, stream>>>(hbuf, wt2, gas[2], gad[2], aux);
    k_gat_attn<<<Gg / GPB, 256, 0, stream>>>(hbuf, aux, gb[2], csr, 1);
    k_gemm_gat<<<Mg / 128, 256, 0, stream>>>(hbuf, wt3, gas[3], gad[3], aux);
    k_gat_attn<<<Gg / GPB, 256, 0, stream>>>(hbuf, aux, gb[3], csr, 0);

    // LSTM layer 0 (hbuf == lstm_in [16384,2176] bf16)
    k_gemm_mfma<<<dim3(Gg / 128, 4), 256, 0, stream>>>(hbuf, wih0b, XW0, bih0, bhh0, LSTM_IN, G4);
    k_lstm<1><<<Bb, 512, 0, stream>>>(XW0, whh0, h1s);
    // LSTM layer 1
    k_gemm_mfma<<<dim3(Gg / 128, 4), 256, 0, stream>>>(h1s, wih1b, XW1, bih1, bhh1, OUT_, G4);
    k_lstm<0><<<Bb, 512, 0, stream>>>(XW1, whh1, h2s);

    k_attn_fc<<<Bb, 64, 0, stream>>>(h2s, attn_w, attn_b, fc_w, fc_b, out);
}

// Round 9
// 829.908 us; speedup vs baseline: 1.3346x; 1.0628x over previous
//
#include <hip/hip_runtime.h>
#include <hip/hip_bf16.h>

// Problem constants
#define Bb 256
#define Nn_ 17
#define CIN 3
#define HID 64
#define CCH 128        // HEADS*HID
#define Gg 16384       // B*S
#define Ee 81          // 64 edges + 17 self loops
#define LSTM_IN 2176   // 17*128
#define OUT_ 128
#define G4 512         // 4*OUT
#define NCLS 10
#define Tt 64
#define Mg (Gg * Nn_)  // 278528

typedef unsigned short u16;
typedef unsigned int u32;
typedef __attribute__((ext_vector_type(8))) short bf16x8;
typedef __attribute__((ext_vector_type(4))) float f32x4;

__device__ __forceinline__ u16 f2bf(float f) {   // RNE fp32->bf16
    u32 u = __float_as_uint(f);
    u += 0x7fffu + ((u >> 16) & 1u);
    return (u16)(u >> 16);
}
__device__ __forceinline__ float bflo(u32 v) { return __uint_as_float(v << 16); }
__device__ __forceinline__ float bfhi(u32 v) { return __uint_as_float(v & 0xffff0000u); }

__device__ __forceinline__ void async16(const void* g, void* l) {
    __builtin_amdgcn_global_load_lds((__attribute__((address_space(1))) u32*)g,
                                     (__attribute__((address_space(3))) u32*)l, 16, 0, 0);
}

// ---------------- setup: build src/dst + dst-CSR
__global__ void k_setup(const int* __restrict__ edge_index, int* __restrict__ csr) {
    if (threadIdx.x == 0 && blockIdx.x == 0) {
        int* src = csr;                    // [81]
        int* dst = csr + Ee;               // [81]
        int* off = csr + 2 * Ee;           // [18]
        int* eid = csr + 2 * Ee + Nn_ + 1; // [81]
        for (int e = 0; e < 64; e++) { src[e] = edge_index[e]; dst[e] = edge_index[64 + e]; }
        for (int n = 0; n < Nn_; n++) { src[64 + n] = n; dst[64 + n] = n; }
        int cnt[Nn_];
        for (int n = 0; n < Nn_; n++) cnt[n] = 0;
        for (int e = 0; e < Ee; e++) cnt[dst[e]]++;
        off[0] = 0;
        for (int n = 0; n < Nn_; n++) off[n + 1] = off[n] + cnt[n];
        int pos[Nn_];
        for (int n = 0; n < Nn_; n++) pos[n] = off[n];
        for (int e = 0; e < Ee; e++) eid[pos[dst[e]]++] = e;
    }
}

__global__ void k_convert(const float* __restrict__ in, u16* __restrict__ out, long n) {
    long i = (long)blockIdx.x * 256 + threadIdx.x;
    if (i < n) out[i] = f2bf(in[i]);
}
// 128x128 weight: [k][n] -> bf16 [n][k] (transpose for MFMA B-operand)
__global__ void k_convert_t128(const float* __restrict__ in, u16* __restrict__ out) {
    int i = blockIdx.x * 256 + threadIdx.x;  // over 16384
    int n = i >> 7, k = i & 127;
    out[i] = f2bf(in[k * 128 + n]);
}

// ---------------- GAT layer 0: h[Mg,128]=x@W0 (bf16) + aux[Mg,4]=x@(W0@a) (fp32)
__global__ __launch_bounds__(256) void k_l0(const float* __restrict__ x,
                                            const float* __restrict__ W0,
                                            const float* __restrict__ gas0,
                                            const float* __restrict__ gad0,
                                            u16* __restrict__ h, float* __restrict__ aux) {
    __shared__ float ws[3 * 128];
    __shared__ float w0a[12];   // [ci][j]  j: src_h0,src_h1,dst_h0,dst_h1
    const int t = threadIdx.x;
    for (int i = t; i < 384; i += 256) ws[i] = W0[i];
    __syncthreads();
    if (t < 12) {
        int ci = t >> 2, j = t & 3;
        const float* a = (j < 2) ? gas0 : gad0;
        int hh = j & 1;
        float s = 0.f;
        for (int d = 0; d < HID; d++) s += ws[ci * 128 + hh * 64 + d] * a[hh * 64 + d];
        w0a[t] = s;
    }
    __syncthreads();
    const long row = (long)blockIdx.x * 16 + (t >> 4);
    const int c0 = (t & 15) * 8;
    const float x0 = x[row * 3 + 0], x1 = x[row * 3 + 1], x2 = x[row * 3 + 2];
    union { uint4 u; u16 s[8]; } o;
#pragma unroll
    for (int j = 0; j < 8; j++)
        o.s[j] = f2bf(x0 * ws[c0 + j] + x1 * ws[128 + c0 + j] + x2 * ws[256 + c0 + j]);
    *(uint4*)(h + row * 128 + c0) = o.u;
    if ((t & 15) < 4) {
        int j = t & 3;
        aux[row * 4 + j] = x0 * w0a[j] + x1 * w0a[4 + j] + x2 * w0a[8 + j];
    }
}

// ---------------- GAT MFMA GEMM (in-place): hbuf = hbuf @ W ; aux = fp32 dots vs a_src/a_dst
// Block = 128 rows, K=128 single pass. A staged to LDS (XOR-swizzled) via global_load_lds;
// B-frags from global (L2-hot 32 KB weight). Dots in FP32 from pre-quantization accumulators.
// In-place safe: full output width per block, row-disjoint blocks, A reads staged before writes.
__global__ __launch_bounds__(256) void k_gemm_gat(u16* __restrict__ HB,
                                                  const u16* __restrict__ Wt,
                                                  const float* __restrict__ a_src,
                                                  const float* __restrict__ a_dst,
                                                  float* __restrict__ aux) {
    __shared__ u16 ldsA[128 * 128];  // 32 KB
    __shared__ float avec[128], dvec[128];
    const int t = threadIdx.x;
    const int w = t >> 6, lane = t & 63;
    const int q = lane >> 4, col = lane & 15;
    const long bm = (long)blockIdx.x * 128;
    const int wm = w * 32;

    if (t < 128) avec[t] = a_src[t];
    else dvec[t - 128] = a_dst[t - 128];

#pragma unroll
    for (int i = 0; i < 8; i++) {
        const int slot = (w * 8 + i) * 64 + lane;
        const int r = slot >> 4, cs = slot & 15;
        const int cg = cs ^ (r & 15);
        async16(HB + (bm + r) * 128 + cg * 8, ldsA + (w * 8 + i) * 512);
    }
    __syncthreads();

    f32x4 acc[2][8] = {};
#pragma unroll
    for (int ks = 0; ks < 4; ks++) {
        const int ck = ks * 4 + q;
        bf16x8 af[2];
#pragma unroll
        for (int mt = 0; mt < 2; mt++) {
            const int m = wm + mt * 16 + col;
            af[mt] = *(const bf16x8*)&ldsA[m * 128 + ((ck ^ (m & 15)) << 3)];
        }
#pragma unroll
        for (int nt = 0; nt < 8; nt++) {
            bf16x8 bf = *(const bf16x8*)&Wt[(nt * 16 + col) * 128 + ck * 8];
            acc[0][nt] = __builtin_amdgcn_mfma_f32_16x16x32_bf16(af[0], bf, acc[0][nt], 0, 0, 0);
            acc[1][nt] = __builtin_amdgcn_mfma_f32_16x16x32_bf16(af[1], bf, acc[1][nt], 0, 0, 0);
        }
    }
    __syncthreads();
#pragma unroll
    for (int mt = 0; mt < 2; mt++) {
#pragma unroll
        for (int nt = 0; nt < 8; nt++) {
            const int cg = nt * 16 + col;
#pragma unroll
            for (int r = 0; r < 4; r++) {
                const long rg = bm + wm + mt * 16 + q * 4 + r;
                HB[rg * 128 + cg] = f2bf(acc[mt][nt][r]);
            }
        }
#pragma unroll
        for (int r = 0; r < 4; r++) {
            float s0 = 0.f, s1 = 0.f, d0 = 0.f, d1 = 0.f;
#pragma unroll
            for (int nt = 0; nt < 4; nt++) {
                const float v = acc[mt][nt][r];
                s0 += v * avec[nt * 16 + col];
                d0 += v * dvec[nt * 16 + col];
            }
#pragma unroll
            for (int nt = 4; nt < 8; nt++) {
                const float v = acc[mt][nt][r];
                s1 += v * avec[nt * 16 + col];
                d1 += v * dvec[nt * 16 + col];
            }
#pragma unroll
            for (int o = 1; o < 16; o <<= 1) {
                s0 += __shfl_xor(s0, o);
                s1 += __shfl_xor(s1, o);
                d0 += __shfl_xor(d0, o);
                d1 += __shfl_xor(d1, o);
            }
            if (col == 0) {
                const long rg = bm + wm + mt * 16 + q * 4 + r;
                aux[rg * 4 + 0] = s0;
                aux[rg * 4 + 1] = s1;
                aux[rg * 4 + 2] = d0;
                aux[rg * 4 + 3] = d1;
            }
        }
    }
}

// ---------------- GAT attention (4 graphs/block)
#define GPB 4
__global__ __launch_bounds__(256) void k_gat_attn(u16* __restrict__ h,
                                                  const float* __restrict__ aux,
                                                  const float* __restrict__ bias,
                                                  const int* __restrict__ csr,
                                                  int relu_flag) {
    __shared__ u32 hs[GPB * Nn_ * 64];
    __shared__ float asd[GPB * Nn_ * 4];     // 272 entries
    __shared__ float ev[GPB][162];
    __shared__ float mS[GPB][34], dS[GPB][34];
    __shared__ float bvec[128];
    __shared__ int srcS[Ee], dstS[Ee], offS[Nn_ + 1], eidS[Ee];
    const int t = threadIdx.x;
    const long g0 = (long)blockIdx.x * GPB;

    if (t < Ee) { srcS[t] = csr[t]; dstS[t] = csr[Ee + t]; eidS[t] = csr[180 + t]; }
    if (t >= 128 && t < 128 + Nn_ + 1) offS[t - 128] = csr[162 + t - 128];
    if (t < 128) bvec[t] = bias[t];
    {
        const u32* hg = (const u32*)h + g0 * 1088;
#pragma unroll
        for (int it = 0; it < 17; it++) hs[t + it * 256] = hg[t + it * 256];
        const float* ag = aux + g0 * 68;
        // BUGFIX (r8): 272 entries > 256 threads; the old `if (t<272)` left
        // asd[256..271] as stale LDS -> nondeterministic replay divergence.
        for (int i = t; i < GPB * Nn_ * 4; i += 256) asd[i] = ag[i];
    }
    __syncthreads();
    for (int i = t; i < GPB * 162; i += 256) {
        const int g = i / 162, rem = i % 162, e = rem >> 1, hh = rem & 1;
        float v = asd[(g * Nn_ + srcS[e]) * 4 + hh] + asd[(g * Nn_ + dstS[e]) * 4 + 2 + hh];
        ev[g][rem] = (v > 0.f) ? v : 0.2f * v;
    }
    __syncthreads();
    if (t < GPB * 34) {
        const int g = t / 34, rem = t % 34, n = rem >> 1, hh = rem & 1;
        const int p0 = offS[n], p1 = offS[n + 1];
        float m = -1e30f;
        for (int p = p0; p < p1; p++) m = fmaxf(m, ev[g][eidS[p] * 2 + hh]);
        float den = 0.f;
        for (int p = p0; p < p1; p++) den += expf(ev[g][eidS[p] * 2 + hh] - m);
        mS[g][rem] = m;
        dS[g][rem] = den;
    }
    __syncthreads();
    for (int i = t; i < GPB * 162; i += 256) {
        const int g = i / 162, rem = i % 162, e = rem >> 1, hh = rem & 1;
        const int n = dstS[e];
        ev[g][rem] = expf(ev[g][rem] - mS[g][n * 2 + hh]) / (dS[g][n * 2 + hh] + 1e-16f);
    }
    __syncthreads();
    u32* hg = (u32*)h + g0 * 1088;
#pragma unroll
    for (int it = 0; it < 17; it++) {
        const int i = t + it * 256;
        const int gg = i / 1088, rr = i % 1088;
        const int n = rr >> 6, cp = rr & 63, hh = cp >> 5;
        const int p0 = offS[n], p1 = offS[n + 1];
        float a0 = 0.f, a1 = 0.f;
        for (int p = p0; p < p1; p++) {
            const int e = eidS[p];
            const u32 hv = hs[(gg * Nn_ + srcS[e]) * 64 + cp];
            const float al = ev[gg][e * 2 + hh];
            a0 += al * bflo(hv);
            a1 += al * bfhi(hv);
        }
        a0 += bvec[cp * 2];
        a1 += bvec[cp * 2 + 1];
        if (relu_flag) { a0 = fmaxf(a0, 0.f); a1 = fmaxf(a1, 0.f); }
        hg[gg * 1088 + n * 64 + cp] = (u32)f2bf(a0) | ((u32)f2bf(a1) << 16);
    }
}

// ---------------- bf16 MFMA GEMM: C[M,ldc] = A[M,K]bf16 @ Bt[N,K]bf16^T + b1[n]+b2[n] (fp32)
__global__ __launch_bounds__(256) void k_gemm_mfma(const u16* __restrict__ A,
                                                   const u16* __restrict__ Bt,
                                                   float* __restrict__ Cm,
                                                   const float* __restrict__ b1,
                                                   const float* __restrict__ b2,
                                                   int K, int ldc) {
    __shared__ u16 ldsA[128 * 64];
    __shared__ u16 ldsB[128 * 64];
    const int w = threadIdx.x >> 6;
    const int lane = threadIdx.x & 63;
    const long bm = (long)blockIdx.x * 128;
    const int bn = blockIdx.y * 128;
    const int wm = (w & 1) * 64, wn = (w >> 1) * 64;
    const int q = lane >> 4, col = lane & 15;
    f32x4 acc[4][4] = {};
    for (int k0 = 0; k0 < K; k0 += 64) {
#pragma unroll
        for (int i = 0; i < 4; i++) {
            const int slot = (w * 4 + i) * 64 + lane;
            const int r = slot >> 3, cs = slot & 7;
            const int cg = cs ^ (r & 7);
            async16(A + (bm + r) * (long)K + k0 + cg * 8, ldsA + (w * 4 + i) * 512);
            async16(Bt + (long)(bn + r) * K + k0 + cg * 8, ldsB + (w * 4 + i) * 512);
        }
        __syncthreads();
#pragma unroll
        for (int kk = 0; kk < 2; kk++) {
            bf16x8 af[4], bfr[4];
#pragma unroll
            for (int mt = 0; mt < 4; mt++) {
                const int m = wm + mt * 16 + col;
                const int cs = (kk * 4 + q) ^ (m & 7);
                af[mt] = *(const bf16x8*)&ldsA[m * 64 + cs * 8];
            }
#pragma unroll
            for (int nt = 0; nt < 4; nt++) {
                const int n = wn + nt * 16 + col;
                const int cs = (kk * 4 + q) ^ (n & 7);
                bfr[nt] = *(const bf16x8*)&ldsB[n * 64 + cs * 8];
            }
#pragma unroll
            for (int mt = 0; mt < 4; mt++)
#pragma unroll
                for (int nt = 0; nt < 4; nt++)
                    acc[mt][nt] = __builtin_amdgcn_mfma_f32_16x16x32_bf16(af[mt], bfr[nt], acc[mt][nt], 0, 0, 0);
        }
        __syncthreads();
    }
#pragma unroll
    for (int mt = 0; mt < 4; mt++)
#pragma unroll
        for (int nt = 0; nt < 4; nt++) {
            const int cg = bn + wn + nt * 16 + col;
            const float bb = b1[cg] + b2[cg];
#pragma unroll
            for (int r = 0; r < 4; r++) {
                const long rg = bm + wm + mt * 16 + q * 4 + r;
                Cm[rg * ldc + cg] = acc[mt][nt][r] + bb;
            }
        }
}

// ---------------- LSTM recurrence (fp32, register whh) + XW[t+1] register prefetch
template <int OBF16>
__global__ __launch_bounds__(512, 1) void k_lstm(const float* __restrict__ XW,
                                                 const float* __restrict__ whh,
                                                 void* __restrict__ hseq) {
    const int b = blockIdx.x, j = threadIdx.x;
    float4 w[32];
#pragma unroll
    for (int k = 0; k < 32; k++) w[k] = ((const float4*)(whh + (long)j * OUT_))[k];
    __shared__ __align__(16) float h_s[OUT_];
    __shared__ float c_s[OUT_];
    __shared__ float gate_s[G4];
    if (j < OUT_) { h_s[j] = 0.f; c_s[j] = 0.f; }
    float xw = XW[((long)b * Tt + 0) * G4 + j];   // prefetch t=0
    __syncthreads();
    for (int t = 0; t < Tt; t++) {
        // issue next step's XW load early -- overlaps the MAC chain + cell math
        float xw_next = 0.f;
        if (t < Tt - 1) xw_next = XW[((long)b * Tt + t + 1) * G4 + j];
        float acc = xw;
#pragma unroll
        for (int k = 0; k < 32; k++) {
            float4 hv = ((const float4*)h_s)[k];
            acc += w[k].x * hv.x + w[k].y * hv.y + w[k].z * hv.z + w[k].w * hv.w;
        }
        gate_s[j] = acc;
        __syncthreads();
        if (j < OUT_) {
            float gi = gate_s[j], gf = gate_s[OUT_ + j], gg = gate_s[2 * OUT_ + j], go = gate_s[3 * OUT_ + j];
            float si = 1.f / (1.f + expf(-gi));
            float sf = 1.f / (1.f + expf(-gf));
            float so = 1.f / (1.f + expf(-go));
            float c = sf * c_s[j] + si * tanhf(gg);
            float hh = so * tanhf(c);
            c_s[j] = c;
            h_s[j] = hh;
            long idx = ((long)b * Tt + t) * OUT_ + j;
            if (OBF16) ((u16*)hseq)[idx] = f2bf(hh);
            else       ((float*)hseq)[idx] = hh;
        }
        xw = xw_next;
        __syncthreads();
    }
}

// ---------------- attention pooling + FC
__global__ __launch_bounds__(64) void k_attn_fc(const float* __restrict__ h2,
                                                const float* __restrict__ attn_w,
                                                const float* __restrict__ attn_b,
                                                const float* __restrict__ fc_w,
                                                const float* __restrict__ fc_b,
                                                float* __restrict__ out) {
    const int b = blockIdx.x, t = threadIdx.x;
    __shared__ float aw[Tt];
    __shared__ float ctx[OUT_];
    const float* hb = h2 + (long)b * Tt * OUT_;
    float acc = 0.f;
    for (int d = 0; d < OUT_; d++) acc += hb[t * OUT_ + d] * attn_w[d];
    float sc = tanhf(acc + attn_b[0]);
    float m = sc;
#pragma unroll
    for (int o = 32; o > 0; o >>= 1) m = fmaxf(m, __shfl_xor(m, o));
    float ex = expf(sc - m);
    float sum = ex;
#pragma unroll
    for (int o = 32; o > 0; o >>= 1) sum += __shfl_xor(sum, o);
    aw[t] = ex / sum;
    __syncthreads();
    for (int d = t; d < OUT_; d += 64) {
        float c = 0.f;
        for (int tt = 0; tt < Tt; tt++) c += aw[tt] * hb[tt * OUT_ + d];
        ctx[d] = c;
    }
    __syncthreads();
    if (t < NCLS) {
        float o = fc_b[t];
        for (int d = 0; d < OUT_; d++) o += ctx[d] * fc_w[t * OUT_ + d];
        out[b * NCLS + t] = o;
    }
}

extern "C" void kernel_launch(void* const* d_in, const int* in_sizes, int n_in,
                              void* d_out, int out_size, void* d_ws, size_t ws_size,
                              hipStream_t stream) {
    const float* x          = (const float*)d_in[0];
    const int*   edge_index = (const int*)d_in[1];
    const float* gw[4]  = {(const float*)d_in[2], (const float*)d_in[6], (const float*)d_in[10], (const float*)d_in[14]};
    const float* gas[4] = {(const float*)d_in[3], (const float*)d_in[7], (const float*)d_in[11], (const float*)d_in[15]};
    const float* gad[4] = {(const float*)d_in[4], (const float*)d_in[8], (const float*)d_in[12], (const float*)d_in[16]};
    const float* gb[4]  = {(const float*)d_in[5], (const float*)d_in[9], (const float*)d_in[13], (const float*)d_in[17]};
    const float* wih0 = (const float*)d_in[18];
    const float* whh0 = (const float*)d_in[19];
    const float* bih0 = (const float*)d_in[20];
    const float* bhh0 = (const float*)d_in[21];
    const float* wih1 = (const float*)d_in[22];
    const float* whh1 = (const float*)d_in[23];
    const float* bih1 = (const float*)d_in[24];
    const float* bhh1 = (const float*)d_in[25];
    const float* attn_w = (const float*)d_in[26];
    const float* attn_b = (const float*)d_in[27];
    const float* fc_w   = (const float*)d_in[28];
    const float* fc_b   = (const float*)d_in[29];
    float* out = (float*)d_out;
    char* p = (char*)d_ws;

    // Workspace (~158 MB; 176.2 MB proven OK in round 2)
    u16*   hbuf  = (u16*)(p + 0L);              // 71,303,168 B
    float* aux   = (float*)(p + 71303168L);     //  4,456,448 B
    float* XW0   = (float*)(p + 75759616L);     // 33,554,432 B
    float* XW1   = (float*)(p + 109314048L);    // 33,554,432 B
    float* h2s   = (float*)(p + 142868480L);    //  8,388,608 B
    u16*   h1s   = (u16*)(p + 151257088L);      //  4,194,304 B
    u16*   wih0b = (u16*)(p + 155451392L);      //  2,228,224 B
    u16*   wih1b = (u16*)(p + 157679616L);      //    131,072 B
    u16*   wt1   = (u16*)(p + 157810688L);      //     32,768 B (x3)
    u16*   wt2   = (u16*)(p + 157843456L);
    u16*   wt3   = (u16*)(p + 157876224L);
    int*   csr   = (int*)(p + 157908992L);      //      1,044 B

    k_setup<<<1, 1, 0, stream>>>(edge_index, csr);
    k_convert_t128<<<64, 256, 0, stream>>>(gw[1], wt1);
    k_convert_t128<<<64, 256, 0, stream>>>(gw[2], wt2);
    k_convert_t128<<<64, 256, 0, stream>>>(gw[3], wt3);
    k_convert<<<(512 * 2176 + 255) / 256, 256, 0, stream>>>(wih0, wih0b, 512L * 2176);
    k_convert<<<(512 * 128 + 255) / 256, 256, 0, stream>>>(wih1, wih1b, 512L * 128);

    // GAT layer 0 projection (+fp32 attn dots) then attention
    k_l0<<<Mg / 16, 256, 0, stream>>>(x, gw[0], gas[0], gad[0], hbuf, aux);
    k_gat_attn<<<Gg / GPB, 256, 0, stream>>>(hbuf, aux, gb[0], csr, 1);
    // layers 1..3: in-place MFMA GEMM with fp32 dot epilogue, then attention
    k_gemm_gat<<<Mg / 128, 256, 0, stream>>>(hbuf, wt1, gas[1], gad[1], aux);
    k_gat_attn<<<Gg / GPB, 256, 0, stream>>>(hbuf, aux, gb[1], csr, 0);
    k_gemm_gat<<<Mg / 128, 256, 0, stream>>>(hbuf, wt2, gas[2], gad[2], aux);
    k_gat_attn<<<Gg / GPB, 256, 0, stream>>>(hbuf, aux, gb[2], csr, 1);
    k_gemm_gat<<<Mg / 128, 256, 0, stream>>>(hbuf, wt3, gas[3], gad[3], aux);
    k_gat_attn<<<Gg / GPB, 256, 0, stream>>>(hbuf, aux, gb[3], csr, 0);

    // LSTM layer 0 (hbuf == lstm_in [16384,2176] bf16)
    k_gemm_mfma<<<dim3(Gg / 128, 4), 256, 0, stream>>>(hbuf, wih0b, XW0, bih0, bhh0, LSTM_IN, G4);
    k_lstm<1><<<Bb, 512, 0, stream>>>(XW0, whh0, h1s);
    // LSTM layer 1
    k_gemm_mfma<<<dim3(Gg / 128, 4), 256, 0, stream>>>(h1s, wih1b, XW1, bih1, bhh1, OUT_, G4);
    k_lstm<0><<<Bb, 512, 0, stream>>>(XW1, whh1, h2s);

    k_attn_fc<<<Bb, 64, 0, stream>>>(h2s, attn_w, attn_b, fc_w, fc_b, out);
}